// Round 9
// baseline (4786.810 us; speedup 1.0000x reference)
//
#include <hip/hip_runtime.h>
#include <hip/hip_bf16.h>

#define NN 768
#define NE 24576
#define NPOS 4096
#define NCELL (NN*NN)   // 589824 = 2304*256
#define GRID 1024       // 256 CUs x 4 blocks/CU; __launch_bounds__(256,4) guarantees residency

typedef __hip_bfloat16 bf16;

__device__ __forceinline__ float ldf(const void* p, int i, int mode) {
    return mode ? __bfloat162float(((const bf16*)p)[i]) : ((const float*)p)[i];
}
__device__ __forceinline__ float aread(float* p) { return atomicAdd(p, 0.f); }

// value-splitting pairwise reduction round (R8-proven)
template<int D, int HALF>
__device__ __forceinline__ void redRound(float* v, int lane) {
#pragma unroll
    for (int i = 0; i < HALF; i++) {
        float snd = (lane & D) ? v[i] : v[i + HALF];
        float r = __shfl_xor(snd, D);
        v[i] = ((lane & D) ? v[i + HALF] : v[i]) + r;
    }
}

#define DOT4(Z, A, W) Z += A.x * W.x + A.y * W.y + A.z * W.z + A.w * W.w

// ---- grid barrier: release-fence + arrive; winner resets & bumps release; spinners acquire ----
__device__ __forceinline__ void gbar(int* arrive, int* release, int k) {
    __syncthreads();
    if (threadIdx.x == 0) {
        __threadfence();
        int ticket = __hip_atomic_fetch_add(arrive, 1, __ATOMIC_ACQ_REL, __HIP_MEMORY_SCOPE_AGENT);
        if (ticket == GRID - 1) {
            __hip_atomic_store(arrive, 0, __ATOMIC_RELAXED, __HIP_MEMORY_SCOPE_AGENT);
            __hip_atomic_fetch_add(release, 1, __ATOMIC_ACQ_REL, __HIP_MEMORY_SCOPE_AGENT);
        } else {
            int guard = 0;
            while (__hip_atomic_load(release, __ATOMIC_ACQUIRE, __HIP_MEMORY_SCOPE_AGENT) < k) {
                __builtin_amdgcn_s_sleep(2);
                if (++guard > (1 << 22)) break;   // bounded: never hang the bench
            }
        }
        __threadfence();
    }
    __syncthreads();
}

// barrier whose winner also finalizes nrm from stats (serial 32 dims, trivial)
__device__ __forceinline__ void gbarNrm(int* arrive, int* release, int k,
                                        float* stats, float* nrm) {
    __syncthreads();
    if (threadIdx.x == 0) {
        __threadfence();
        int ticket = __hip_atomic_fetch_add(arrive, 1, __ATOMIC_ACQ_REL, __HIP_MEMORY_SCOPE_AGENT);
        if (ticket == GRID - 1) {
            __threadfence();
            float cmv = aread(&stats[64]);
            if (cmv < 1.f) cmv = 1.f;
            for (int d = 0; d < 32; d++) {
                float m = aread(&stats[d]) / cmv;
                float var = aread(&stats[32 + d]) / cmv - m * m;
                nrm[d] = m;
                nrm[32 + d] = rsqrtf(fmaxf(var, 0.f) + 1e-5f);
            }
            __threadfence();
            __hip_atomic_store(arrive, 0, __ATOMIC_RELAXED, __HIP_MEMORY_SCOPE_AGENT);
            __hip_atomic_fetch_add(release, 1, __ATOMIC_ACQ_REL, __HIP_MEMORY_SCOPE_AGENT);
        } else {
            int guard = 0;
            while (__hip_atomic_load(release, __ATOMIC_ACQUIRE, __HIP_MEMORY_SCOPE_AGENT) < k) {
                __builtin_amdgcn_s_sleep(2);
                if (++guard > (1 << 22)) break;
            }
        }
        __threadfence();
    }
    __syncthreads();
}

// ---------------- init: zero barrier counters + small state ----------------
__global__ void k_init0(int* __restrict__ arrive, int* __restrict__ release,
                        int* __restrict__ ctrs, int* __restrict__ dcs,
                        float* __restrict__ stats, int* __restrict__ cursor,
                        int* __restrict__ rowlen) {
    int t = threadIdx.x;
    if (t == 0) { *arrive = 0; *release = 0; }
    if (t < 8) { ctrs[t] = 0; dcs[t] = 0; }
    if (t < 66) stats[t] = 0.f;
    for (int i = t; i < NN; i += 256) { cursor[i] = 0; rowlen[i] = 0; }
}

// ---------------- the persistent mega-kernel ----------------
__global__ __launch_bounds__(256, 4) void k_mega(
    const int* __restrict__ x, const int* __restrict__ ei, const int* __restrict__ pos,
    const void* __restrict__ emb, const void* __restrict__ gW, const void* __restrict__ gB,
    const void* __restrict__ m1W, const void* __restrict__ m1B,
    const void* __restrict__ m2W, const void* __restrict__ m2B,
    const void* __restrict__ m3W, const void* __restrict__ m3B,
    const void* __restrict__ lW, const void* __restrict__ lB,
    int* __restrict__ cell, int* __restrict__ pcur, int* __restrict__ rowlen,
    int* __restrict__ row_ptr, int* __restrict__ col_idx, float* __restrict__ cntv,
    int* __restrict__ pr_row, int* __restrict__ cursor, float* __restrict__ dinv,
    float* __restrict__ h, float* __restrict__ bufA, float* __restrict__ bufB,
    float* __restrict__ xep, float* __restrict__ mulp,
    float* __restrict__ stats, float* __restrict__ nrm,
    float* __restrict__ nrm0, float* __restrict__ nrm1,
    float* __restrict__ gwf, float* __restrict__ gbf,
    float* __restrict__ w1f, float* __restrict__ b1f,
    float* __restrict__ w2f, float* __restrict__ b2f,
    float* __restrict__ w3q, float* __restrict__ linf, float* __restrict__ linb,
    int* __restrict__ modeg, int* arrive, int* release, int* ctrs, int* dcs,
    int* __restrict__ bsum, int* __restrict__ boff,
    int2* __restrict__ paths2, int cap, void* __restrict__ outp)
{
    __shared__ int   sI[772];          // scans + chunk broadcast (sI[771])
    __shared__ float sF[512];          // stats tails / out Cb
    __shared__ float sS1[32], sS2[32];
    __shared__ float sCm;
    __shared__ int   sBad;
    int t = threadIdx.x;
    int bid = blockIdx.x;
    int lane = t & 63;

    // ======== phase 0: clears (bid<1023) | detect+conv (bid 1023) ========
    if (bid == GRID - 1) {
        if (t == 0) sBad = 0;
        __syncthreads();
        int local = 0;
        for (int i = t; i < 3232; i += 256) {
            float a = fabsf(__bfloat162float(((const bf16*)emb)[i]));
            if (!(a < 100.f)) local = 1;
        }
        if (local) atomicOr(&sBad, 1);
        __syncthreads();
        int mode = sBad ? 0 : 1;
        if (t == 0) *modeg = mode;
        for (int i = t; i < 2048; i += 256) {
            gwf[i] = ldf(gW, i, mode);
            w1f[i] = ldf(m1W, i, mode);
            w2f[i] = ldf(m2W, i, mode);
        }
        for (int i = t; i < 64; i += 256) { gbf[i] = ldf(gB, i, mode); linf[i] = ldf(lW, i, mode); }
        if (t < 32) { b1f[t] = ldf(m1B, t, mode); b2f[t] = ldf(m2B, t, mode); }
        for (int i = t; i < 1056; i += 256) { int c = i >> 5, d = i & 31; w3q[d * 36 + c] = ldf(m3W, i, mode); }
        if (t < 32) { w3q[t * 36 + 33] = ldf(m3B, t, mode); w3q[t * 36 + 34] = 0.f; w3q[t * 36 + 35] = 0.f; }
        if (t == 0) linb[0] = ldf(lB, 0, mode);
    } else {
        for (int idx = bid * 256 + t; idx < NCELL; idx += (GRID - 1) * 256) cell[idx] = 0;
        for (int idx = bid * 256 + t; idx < NCELL; idx += (GRID - 1) * 256) pcur[idx] = 0;
    }
    gbar(arrive, release, 1);

    // ======== phase 1: edge scatter ========
    if (bid < 96) {
        int e = bid * 256 + t;
        int a = ei[e], b = ei[NE + e];
        if ((unsigned)a < (unsigned)NN && (unsigned)b < (unsigned)NN) {
            int old = atomicAdd(&cell[a * NN + b], 1);
            if (old == 0) atomicAdd(&rowlen[a], 1);
        }
    }
    gbar(arrive, release, 2);

    // ======== phase 2: row scan (bid 0) | matw0 (bid 1..96) ========
    if (bid == 0) {
        int i0 = 3 * t;
        int r0 = rowlen[i0], r1 = rowlen[i0 + 1], r2 = rowlen[i0 + 2];
        dinv[i0]     = rsqrtf((float)r0 + 1.f);
        dinv[i0 + 1] = rsqrtf((float)r1 + 1.f);
        dinv[i0 + 2] = rsqrtf((float)r2 + 1.f);
        int s3 = r0 + r1 + r2;
        sI[t] = s3;
        __syncthreads();
        for (int off = 1; off < 256; off <<= 1) {
            int tmp = (t >= off) ? sI[t - off] : 0;
            __syncthreads();
            sI[t] += tmp;
            __syncthreads();
        }
        int excl = sI[t] - s3;
        row_ptr[i0] = excl;
        row_ptr[i0 + 1] = excl + r0;
        row_ptr[i0 + 2] = excl + r0 + r1;
        if (t == 255) row_ptr[NN] = sI[255];
    } else if (bid <= 96) {
        int idx = (bid - 1) * 256 + t;
        int i = idx >> 5, d = idx & 31;
        int mode = *modeg;
        int xi = x[i]; if (xi < 0) xi = 0; if (xi > 100) xi = 100;
        float s = 0.f;
#pragma unroll
        for (int c = 0; c < 32; c++) s += ldf(emb, xi * 32 + c, mode) * gwf[c * 32 + d];
        bufA[idx] = s;
    }
    gbar(arrive, release, 3);

    // ======== phase 3: CSR fill (dynamic, 2304 chunks) ========
    for (;;) {
        __syncthreads();
        if (t == 0) sI[771] = atomicAdd(&ctrs[0], 1);
        __syncthreads();
        int c = sI[771];
        if (c >= 2304) break;
        int idx = c * 256 + t;
        int i = idx / NN;
        int j = idx - i * NN;
        int cv = cell[idx];
        if (cv > 0) {
            int p = row_ptr[i] + atomicAdd(&cursor[i], 1);
            col_idx[p] = j; cntv[p] = (float)cv; pr_row[p] = i;
            cell[idx] = p;
        } else cell[idx] = -1;
    }
    gbar(arrive, release, 4);

    // ======== phase 4: path count (dynamic, 6144) ; then agg0 (bid<96) + nrm0 winner ========
    {
        int npairs = row_ptr[NN];
        for (;;) {
            __syncthreads();
            if (t == 0) sI[771] = atomicAdd(&ctrs[1], 1);
            __syncthreads();
            int c = sI[771];
            if (c >= 6144) break;
            int wid = c * 4 + (t >> 6);
            if (wid < npairs) {
                int i = pr_row[wid], k = col_idx[wid];
                int base = i * NN;
                int kb = row_ptr[k], ke = row_ptr[k + 1];
                for (int e = kb + lane; e < ke; e += 64) atomicAdd(&pcur[base + col_idx[e]], 1);
            }
        }
    }
    if (bid < 96) {
        int idx = bid * 256 + t;
        int i = idx >> 5, d = idx & 31;
        int base = row_ptr[i], len = row_ptr[i + 1] - base;
        float di = dinv[i];
        float acc = di * bufA[i * 32 + d];
        for (int e = 0; e < len; e++) { int c = col_idx[base + e]; acc += dinv[c] * bufA[c * 32 + d]; }
        bufB[idx] = di * acc + gbf[d];
        __syncthreads();
        if (t == 0) {
            __threadfence();
            sI[771] = (__hip_atomic_fetch_add(&dcs[0], 1, __ATOMIC_ACQ_REL, __HIP_MEMORY_SCOPE_AGENT) == 95) ? 1 : 0;
        }
        __syncthreads();
        if (sI[771]) {
            if (t == 0) __threadfence();
            __syncthreads();
            int dd = t & 31, g = t >> 5;
            float s = 0.f, s2 = 0.f;
            for (int r = g; r < NN; r += 8) { float v = bufB[r * 32 + dd]; s += v; s2 += v * v; }
            sF[t] = s; sF[256 + t] = s2;
            __syncthreads();
            if (t < 32) {
                float a = 0.f, b2 = 0.f;
                for (int q = 0; q < 8; q++) { a += sF[q * 32 + t]; b2 += sF[256 + q * 32 + t]; }
                float mean = a / (float)NN;
                float var = b2 / (float)NN - mean * mean;
                nrm0[t] = mean;
                nrm0[32 + t] = rsqrtf(fmaxf(var, 0.f) + 1e-5f);
            }
        }
    }
    gbar(arrive, release, 5);

    // ======== phase 5: per-chunk scan of pcur (dynamic, 2304) ========
    for (;;) {
        __syncthreads();
        if (t == 0) sI[771] = atomicAdd(&ctrs[2], 1);
        __syncthreads();
        int c = sI[771];
        if (c >= 2304) break;
        int n = c * 256 + t;
        int v = pcur[n];
        sI[t] = v;
        __syncthreads();
        for (int off = 1; off < 256; off <<= 1) {
            int tmp = (t >= off) ? sI[t - off] : 0;
            __syncthreads();
            sI[t] += tmp;
            __syncthreads();
        }
        pcur[n] = sI[t] - v;
        if (t == 255) bsum[c] = sI[255];
    }
    gbar(arrive, release, 6);

    // ======== phase 6: block-sum scan (bid 0) | matw1 w/ inline norm0 (bid 1..96) ========
    if (bid == 0) {
        int b9[9]; int s9 = 0;
#pragma unroll
        for (int q = 0; q < 9; q++) { b9[q] = bsum[t * 9 + q]; s9 += b9[q]; }
        sI[t] = s9;
        __syncthreads();
        for (int off = 1; off < 256; off <<= 1) {
            int tmp = (t >= off) ? sI[t - off] : 0;
            __syncthreads();
            sI[t] += tmp;
            __syncthreads();
        }
        int run = sI[t] - s9;
#pragma unroll
        for (int q = 0; q < 9; q++) { boff[t * 9 + q] = run; run += b9[q]; }
    } else if (bid <= 96) {
        int idx = (bid - 1) * 256 + t;
        int i = idx >> 5, d = idx & 31;
        const float* W = gwf + 1024;
        float s = 0.f;
#pragma unroll
        for (int c = 0; c < 32; c++) {
            float hv = fmaxf((bufB[i * 32 + c] - nrm0[c]) * nrm0[32 + c], 0.f);
            s += hv * W[c * 32 + d];
        }
        bufA[idx] = s;
    }
    gbar(arrive, release, 7);

    // ======== phase 7: path join (dynamic, 6144) ; then agg1 (bid<96) + nrm1 winner ========
    {
        int npairs = row_ptr[NN];
        for (;;) {
            __syncthreads();
            if (t == 0) sI[771] = atomicAdd(&ctrs[3], 1);
            __syncthreads();
            int c = sI[771];
            if (c >= 6144) break;
            int wid = c * 4 + (t >> 6);
            if (wid < npairs) {
                int i = pr_row[wid], k = col_idx[wid];
                int base = i * NN;
                int kb = row_ptr[k], ke = row_ptr[k + 1];
                for (int e = kb + lane; e < ke; e += 64) {
                    int celln = base + col_idx[e];
                    int slot = boff[celln >> 8] + atomicAdd(&pcur[celln], 1);
                    if (slot < cap) paths2[slot] = make_int2(wid, e);
                }
            }
        }
    }
    if (bid < 96) {
        int idx = bid * 256 + t;
        int i = idx >> 5, d = idx & 31;
        int base = row_ptr[i], len = row_ptr[i + 1] - base;
        float di = dinv[i];
        float acc = di * bufA[i * 32 + d];
        for (int e = 0; e < len; e++) { int c = col_idx[base + e]; acc += dinv[c] * bufA[c * 32 + d]; }
        bufB[idx] = di * acc + gbf[32 + d];
        __syncthreads();
        if (t == 0) {
            __threadfence();
            sI[771] = (__hip_atomic_fetch_add(&dcs[1], 1, __ATOMIC_ACQ_REL, __HIP_MEMORY_SCOPE_AGENT) == 95) ? 1 : 0;
        }
        __syncthreads();
        if (sI[771]) {
            if (t == 0) __threadfence();
            __syncthreads();
            int dd = t & 31, g = t >> 5;
            float s = 0.f, s2 = 0.f;
            for (int r = g; r < NN; r += 8) { float v = bufB[r * 32 + dd]; s += v; s2 += v * v; }
            sF[t] = s; sF[256 + t] = s2;
            __syncthreads();
            if (t < 32) {
                float a = 0.f, b2 = 0.f;
                for (int q = 0; q < 8; q++) { a += sF[q * 32 + t]; b2 += sF[256 + q * 32 + t]; }
                float mean = a / (float)NN;
                float var = b2 / (float)NN - mean * mean;
                nrm1[t] = mean;
                nrm1[32 + t] = rsqrtf(fmaxf(var, 0.f) + 1e-5f);
            }
        }
    }
    gbar(arrive, release, 8);

    // ======== phase 8: edge MLP w/ inline norm1 (dynamic, 3072) ; h write (bid<96) ========
    {
        int npairs = row_ptr[NN];
        for (;;) {
            __syncthreads();
            if (t == 0) sI[771] = atomicAdd(&ctrs[4], 1);
            __syncthreads();
            int c = sI[771];
            if (c >= 3072) break;
            int d = t & 31;
            int p = c * 8 + (t >> 5);
            if (p >= npairs) {
                if (p < NE) { xep[p * 32 + d] = 0.f; mulp[p * 32 + d] = 0.f; }
            } else {
                int i = pr_row[p], j = col_idx[p];
                float a1 = b1f[d], a2 = b2f[d];
#pragma unroll
                for (int c2 = 0; c2 < 32; c2++) {
                    float hv = fmaxf((bufB[i * 32 + c2] - nrm1[c2]) * nrm1[32 + c2], 0.f);
                    a1 += hv * w1f[c2 * 32 + d];
                    a2 += hv * w2f[c2 * 32 + d];
                }
#pragma unroll
                for (int c2 = 0; c2 < 32; c2++) {
                    float hv = fmaxf((bufB[j * 32 + c2] - nrm1[c2]) * nrm1[32 + c2], 0.f);
                    a1 += hv * w1f[(32 + c2) * 32 + d];
                    a2 += hv * w2f[(32 + c2) * 32 + d];
                }
                float cv = cntv[p];
                xep[p * 32 + d]  = cv * fmaxf(a1, 0.f);
                mulp[p * 32 + d] = cv * fmaxf(a2, 0.f);
            }
        }
    }
    if (bid < 96) {
        int idx = bid * 256 + t;
        int d = idx & 31;
        h[idx] = fmaxf((bufB[idx] - nrm1[d]) * nrm1[32 + d], 0.f);
    }
    gbar(arrive, release, 9);

    // ======== phase 9: big pass (dynamic, 2304 chunks; R8-proven body) ========
    for (;;) {
        __syncthreads();
        if (t == 0) sI[771] = atomicAdd(&ctrs[5], 1);
        __syncthreads();
        int c = sI[771];
        if (c >= 2304) break;
        if (t == 0) sCm = 0.f;
        if (t < 32) { sS1[t] = 0.f; sS2[t] = 0.f; }
        __syncthreads();
        int n = c * 256 + t;
        int bo = boff[c];
        int p1 = bo + pcur[n];
        int p0 = (t == 0) ? bo : bo + pcur[n - 1];
        if (p0 > cap) p0 = cap; if (p1 > cap) p1 = cap;
        float4 a0 = {0.f,0.f,0.f,0.f}, a1 = a0, a2 = a0, a3 = a0, a4 = a0, a5 = a0, a6 = a0, a7 = a0;
        const float4* xep4 = (const float4*)xep;
        const float4* mulp4 = (const float4*)mulp;
        for (int p = p0; p < p1; p++) {
            int2 rec = paths2[p];
            const float4* xr = xep4 + rec.x * 8;
            const float4* mr = mulp4 + rec.y * 8;
            float4 xv, mv;
            xv = xr[0]; mv = mr[0]; a0.x += xv.x*mv.x; a0.y += xv.y*mv.y; a0.z += xv.z*mv.z; a0.w += xv.w*mv.w;
            xv = xr[1]; mv = mr[1]; a1.x += xv.x*mv.x; a1.y += xv.y*mv.y; a1.z += xv.z*mv.z; a1.w += xv.w*mv.w;
            xv = xr[2]; mv = mr[2]; a2.x += xv.x*mv.x; a2.y += xv.y*mv.y; a2.z += xv.z*mv.z; a2.w += xv.w*mv.w;
            xv = xr[3]; mv = mr[3]; a3.x += xv.x*mv.x; a3.y += xv.y*mv.y; a3.z += xv.z*mv.z; a3.w += xv.w*mv.w;
            xv = xr[4]; mv = mr[4]; a4.x += xv.x*mv.x; a4.y += xv.y*mv.y; a4.z += xv.z*mv.z; a4.w += xv.w*mv.w;
            xv = xr[5]; mv = mr[5]; a5.x += xv.x*mv.x; a5.y += xv.y*mv.y; a5.z += xv.z*mv.z; a5.w += xv.w*mv.w;
            xv = xr[6]; mv = mr[6]; a6.x += xv.x*mv.x; a6.y += xv.y*mv.y; a6.z += xv.z*mv.z; a6.w += xv.w*mv.w;
            xv = xr[7]; mv = mr[7]; a7.x += xv.x*mv.x; a7.y += xv.y*mv.y; a7.z += xv.z*mv.z; a7.w += xv.w*mv.w;
        }
        bool adj = cell[n] >= 0;
        float af = adj ? 1.f : 0.f;
        float msk = (p1 > p0 || adj) ? 1.f : 0.f;
#pragma unroll
        for (int ch = 0; ch < 2; ch++) {
            float v[32];
#pragma unroll
            for (int j = 0; j < 16; j++) {
                int dd = ch * 16 + j;
                const float4* wr = (const float4*)(w3q + dd * 36);   // wave-uniform -> s_load
                float4 wv = wr[8];
                float z = wv.y + af * wv.x;
                wv = wr[0]; DOT4(z, a0, wv);
                wv = wr[1]; DOT4(z, a1, wv);
                wv = wr[2]; DOT4(z, a2, wv);
                wv = wr[3]; DOT4(z, a3, wv);
                wv = wr[4]; DOT4(z, a4, wv);
                wv = wr[5]; DOT4(z, a5, wv);
                wv = wr[6]; DOT4(z, a6, wv);
                wv = wr[7]; DOT4(z, a7, wv);
                v[j] = msk * z;
                v[16 + j] = msk * z * z;
            }
#pragma unroll
            for (int i2 = 0; i2 < 32; i2++) v[i2] += __shfl_xor(v[i2], 32);
            redRound<16, 16>(v, lane);
            redRound<8, 8>(v, lane);
            redRound<4, 4>(v, lane);
            redRound<2, 2>(v, lane);
            redRound<1, 1>(v, lane);
            if (lane < 32) {
                if (lane < 16) atomicAdd(&sS1[ch * 16 + lane], v[0]);
                else           atomicAdd(&sS2[ch * 16 + lane - 16], v[0]);
            }
        }
        {
            float cm2 = msk;
            for (int off = 32; off >= 1; off >>= 1) cm2 += __shfl_xor(cm2, off);
            if (lane == 0) atomicAdd(&sCm, cm2);
        }
        __syncthreads();
        if (t < 32) {
            atomicAdd(&stats[t], sS1[t]);
            atomicAdd(&stats[32 + t], sS2[t]);
        }
        if (t == 32) atomicAdd(&stats[64], sCm);
    }
    gbarNrm(arrive, release, 10, stats, nrm);

    // ======== phase 10: output (1024 chunks = 1 per block) ========
    {
        int w = t >> 6, d = lane & 31, dir = lane >> 5;
        int p = bid * 4 + w;
        int a = pos[2 * p], b = pos[2 * p + 1];
        if ((unsigned)a >= (unsigned)NN) a = 0;
        if ((unsigned)b >= (unsigned)NN) b = 0;
        int r = dir ? b : a;
        int cc = dir ? a : b;
        int n = r * NN + cc;
        int nb = n >> 8;
        int p1 = boff[nb] + pcur[n];
        int p0 = ((n & 255) == 0) ? boff[nb] : boff[nb] + pcur[n - 1];
        if (p0 > cap) p0 = cap; if (p1 > cap) p1 = cap;
        float acc = 0.f;
        for (int q = p0; q < p1; q++) {
            int2 rec = paths2[q];
            acc += xep[rec.x * 32 + d] * mulp[rec.y * 32 + d];
        }
        sF[w * 64 + dir * 32 + d] = acc;
        bool adj = cell[n] >= 0;
        float msk = (p1 > p0 || adj) ? 1.f : 0.f;
        __syncthreads();
        float z = w3q[d * 36 + 33] + (adj ? 1.f : 0.f) * w3q[d * 36 + 32];
#pragma unroll
        for (int c = 0; c < 32; c++) z += sF[w * 64 + dir * 32 + c] * w3q[d * 36 + c];
        float zn = fmaxf((z - nrm[d]) * nrm[32 + d], 0.f);
        float zp = __shfl_xor(zn, 32);
        float symd = msk * zn * zp;
        float xxd = h[a * 32 + d] * h[b * 32 + d];
        float contrib = symd * linf[d] + xxd * linf[32 + d];
        for (int off = 16; off >= 1; off >>= 1) contrib += __shfl_xor(contrib, off);
        if (lane == 0) {
            float v = contrib + linb[0];
            v = fminf(fmaxf(v, -1e4f), 1e4f);
            if (*modeg) ((bf16*)outp)[p] = __float2bfloat16(v);
            else        ((float*)outp)[p] = v;
        }
    }
}

extern "C" void kernel_launch(void* const* d_in, const int* in_sizes, int n_in,
                              void* d_out, int out_size, void* d_ws, size_t ws_size,
                              hipStream_t stream) {
    const void* px  = d_in[0];  const void* pei = d_in[1];  const void* ppos = d_in[2];
    const void* pemb = d_in[3]; const void* pgW = d_in[4];  const void* pgB  = d_in[5];
    const void* pm1W = d_in[6]; const void* pm1B = d_in[7]; const void* pm2W = d_in[8];
    const void* pm2B = d_in[9]; const void* pm3W = d_in[10]; const void* pm3B = d_in[11];
    const void* plW = d_in[12]; const void* plB = d_in[13];
    {
        int c2048 = 0, c64 = 0, c32 = 0;
        for (int i = 0; i < n_in; i++) {
            int s = in_sizes[i]; const void* p = d_in[i];
            switch (s) {
                case 768:   px = p; break;
                case 49152: pei = p; break;
                case 8192:  ppos = p; break;
                case 3232:  pemb = p; break;
                case 2048:  if (c2048 == 0) pgW = p; else if (c2048 == 1) pm1W = p; else pm2W = p; c2048++; break;
                case 64:    if (c64 == 0) pgB = p; else plW = p; c64++; break;
                case 32:    if (c32 == 0) pm1B = p; else if (c32 == 1) pm2B = p; else pm3B = p; c32++; break;
                case 1056:  pm3W = p; break;
                case 1:     plB = p; break;
                default: break;
            }
        }
    }

    char* ws = (char*)d_ws;
    size_t off = 0;
    auto alloc = [&](size_t bytes) -> void* {
        void* pp = ws + off;
        off += (bytes + 255) & ~(size_t)255;
        return pp;
    };
    int*   cell    = (int*)alloc(NCELL * 4);
    int*   pcur    = (int*)alloc(NCELL * 4);
    int*   rowlen  = (int*)alloc(NN * 4);
    int*   row_ptr = (int*)alloc((NN + 1) * 4);
    int*   col_idx = (int*)alloc(NE * 4);
    float* cntv    = (float*)alloc(NE * 4);
    int*   pr_row  = (int*)alloc(NE * 4);
    int*   cursor  = (int*)alloc(NN * 4);
    float* dinv    = (float*)alloc(NN * 4);
    float* h       = (float*)alloc(NN * 32 * 4);
    float* bufA    = (float*)alloc(NN * 32 * 4);
    float* bufB    = (float*)alloc(NN * 32 * 4);
    float* xep     = (float*)alloc(NE * 32 * 4);
    float* mulp    = (float*)alloc(NE * 32 * 4);
    float* stats   = (float*)alloc(66 * 4);
    float* nrm     = (float*)alloc(64 * 4);
    float* nrm0    = (float*)alloc(64 * 4);
    float* nrm1    = (float*)alloc(64 * 4);
    float* gwf     = (float*)alloc(2048 * 4);
    float* gbf     = (float*)alloc(64 * 4);
    float* w1f     = (float*)alloc(2048 * 4);
    float* b1f     = (float*)alloc(32 * 4);
    float* w2f     = (float*)alloc(2048 * 4);
    float* b2f     = (float*)alloc(32 * 4);
    float* w3q     = (float*)alloc(32 * 36 * 4);
    float* linf    = (float*)alloc(64 * 4);
    float* linb    = (float*)alloc(4);
    int*   modeg   = (int*)alloc(4);
    int*   arrive  = (int*)alloc(4);
    int*   release = (int*)alloc(4);
    int*   ctrs    = (int*)alloc(8 * 4);
    int*   dcs     = (int*)alloc(8 * 4);
    int*   bsum    = (int*)alloc(2304 * 4);
    int*   boff    = (int*)alloc(2304 * 4);
    size_t remain = (ws_size > off) ? (ws_size - off) : 0;
    int cap = (int)(remain / 8);
    if (cap > (1 << 20)) cap = (1 << 20);
    int2*  paths2  = (int2*)alloc((size_t)cap * 8);

    k_init0<<<1, 256, 0, stream>>>(arrive, release, ctrs, dcs, stats, cursor, rowlen);
    k_mega<<<GRID, 256, 0, stream>>>(
        (const int*)px, (const int*)pei, (const int*)ppos,
        pemb, pgW, pgB, pm1W, pm1B, pm2W, pm2B, pm3W, pm3B, plW, plB,
        cell, pcur, rowlen, row_ptr, col_idx, cntv, pr_row, cursor, dinv,
        h, bufA, bufB, xep, mulp, stats, nrm, nrm0, nrm1,
        gwf, gbf, w1f, b1f, w2f, b2f, w3q, linf, linb,
        modeg, arrive, release, ctrs, dcs, bsum, boff, paths2, cap, d_out);
}

// Round 10
// 409.609 us; speedup vs baseline: 11.6863x; 11.6863x over previous
//
#include <hip/hip_runtime.h>
#include <hip/hip_bf16.h>

#define NN 768
#define NE 24576
#define NPOS 4096
#define NCELL (NN*NN)   // 589824 = 2304*256
#define NBLK 2304
#define NREP 16         // stats replicas (contention spread)

typedef __hip_bfloat16 bf16;

__device__ __forceinline__ float ldf(const void* p, int i, int mode) {
    return mode ? __bfloat162float(((const bf16*)p)[i]) : ((const float*)p)[i];
}
__device__ __forceinline__ float aread(float* p) { return atomicAdd(p, 0.f); }
__device__ __forceinline__ int areadi(int* p) { return atomicAdd(p, 0); }

// value-splitting pairwise reduction round (R8-proven)
template<int D, int HALF>
__device__ __forceinline__ void redRound(float* v, int lane) {
#pragma unroll
    for (int i = 0; i < HALF; i++) {
        float snd = (lane & D) ? v[i] : v[i + HALF];
        float r = __shfl_xor(snd, D);
        v[i] = ((lane & D) ? v[i + HALF] : v[i]) + r;
    }
}

#define DOT4(Z, A, W) Z += A.x * W.x + A.y * W.y + A.z * W.z + A.w * W.w

// ---------------- conv (block 0) + aux clear (block 1) ----------------
__global__ void k_conv(const void* __restrict__ gW, const void* __restrict__ gB,
                       const void* __restrict__ m1W, const void* __restrict__ m1B,
                       const void* __restrict__ m2W, const void* __restrict__ m2B,
                       const void* __restrict__ m3W, const void* __restrict__ m3B,
                       const void* __restrict__ lW,  const void* __restrict__ lB,
                       const void* __restrict__ emb,
                       float* __restrict__ stats, int* __restrict__ cursor,
                       int* __restrict__ rowlen, int* __restrict__ dcs,
                       int* __restrict__ modeg,
                       float* __restrict__ gwf, float* __restrict__ gbf,
                       float* __restrict__ w1f, float* __restrict__ b1f,
                       float* __restrict__ w2f, float* __restrict__ b2f,
                       float* __restrict__ w3q, float* __restrict__ linf, float* __restrict__ linb) {
    int t = threadIdx.x;
    if (blockIdx.x == 1) {
        for (int i = t; i < NN; i += 256) { cursor[i] = 0; rowlen[i] = 0; }
        for (int i = t; i < NREP * 80; i += 256) stats[i] = 0.f;
        if (t < 8) dcs[t] = 0;
        return;
    }
    __shared__ int bad;
    if (t == 0) bad = 0;
    __syncthreads();
    int local = 0;
    for (int i = t; i < 3232; i += 256) {
        float a = fabsf(__bfloat162float(((const bf16*)emb)[i]));
        if (!(a < 100.f)) local = 1;
    }
    if (local) atomicOr(&bad, 1);
    __syncthreads();
    int mode = bad ? 0 : 1;
    if (t == 0) *modeg = mode;
    for (int i = t; i < 2048; i += 256) {
        gwf[i] = ldf(gW, i, mode);
        w1f[i] = ldf(m1W, i, mode);
        w2f[i] = ldf(m2W, i, mode);
    }
    for (int i = t; i < 64; i += 256) { gbf[i] = ldf(gB, i, mode); linf[i] = ldf(lW, i, mode); }
    if (t < 32) { b1f[t] = ldf(m1B, t, mode); b2f[t] = ldf(m2B, t, mode); }
    // w3q row d (stride 36 floats, 16B-aligned): [W3[0..31][d], ind, b3, 0, 0]
    for (int i = t; i < 1056; i += 256) { int c = i >> 5, d = i & 31; w3q[d * 36 + c] = ldf(m3W, i, mode); }
    if (t < 32) { w3q[t * 36 + 33] = ldf(m3B, t, mode); w3q[t * 36 + 34] = 0.f; w3q[t * 36 + 35] = 0.f; }
    if (t == 0) linb[0] = ldf(lB, 0, mode);
}

// ---------------- edge scatter; last block: row scan + dinv (R6-proven fold) ----------------
__global__ void k_scatter(const int* __restrict__ ei, int* __restrict__ cell, int* __restrict__ rowlen,
                          int* __restrict__ row_ptr, float* __restrict__ dinv, int* __restrict__ dc) {
    __shared__ int amlast;
    __shared__ int sI[256];
    int t = threadIdx.x;
    int e = blockIdx.x * 256 + t;
    int a = ei[e], b = ei[NE + e];
    if ((unsigned)a < (unsigned)NN && (unsigned)b < (unsigned)NN) {
        int old = atomicAdd(&cell[a * NN + b], 1);
        if (old == 0) atomicAdd(&rowlen[a], 1);
    }
    __syncthreads();
    if (t == 0) { __threadfence(); amlast = (atomicAdd(dc, 1) == 95) ? 1 : 0; }
    __syncthreads();
    if (!amlast) return;
    int i0 = 3 * t;
    int r0 = areadi(&rowlen[i0]), r1 = areadi(&rowlen[i0 + 1]), r2 = areadi(&rowlen[i0 + 2]);
    dinv[i0]     = rsqrtf((float)r0 + 1.f);
    dinv[i0 + 1] = rsqrtf((float)r1 + 1.f);
    dinv[i0 + 2] = rsqrtf((float)r2 + 1.f);
    int s3 = r0 + r1 + r2;
    sI[t] = s3;
    __syncthreads();
    for (int off = 1; off < 256; off <<= 1) {
        int tmp = (t >= off) ? sI[t - off] : 0;
        __syncthreads();
        sI[t] += tmp;
        __syncthreads();
    }
    int excl = sI[t] - s3;
    row_ptr[i0] = excl;
    row_ptr[i0 + 1] = excl + r0;
    row_ptr[i0 + 2] = excl + r0 + r1;
    if (t == 255) row_ptr[NN] = sI[255];
}

// ---------------- CSR fill (b<2304) || matw0 (b>=2304) ----------------
__global__ void k_fw0(int* __restrict__ cell, const int* __restrict__ row_ptr, int* __restrict__ cursor,
                      int* __restrict__ col_idx, float* __restrict__ cntv, int* __restrict__ pr_row,
                      const int* __restrict__ x, const void* __restrict__ emb,
                      const int* __restrict__ modep, const float* __restrict__ gwf,
                      float* __restrict__ bufA) {
    int t = threadIdx.x;
    int b = blockIdx.x;
    if (b < NBLK) {
        int idx = b * 256 + t;
        int i = idx / NN;
        int j = idx - i * NN;
        int cv = cell[idx];
        if (cv > 0) {
            int p = row_ptr[i] + atomicAdd(&cursor[i], 1);
            col_idx[p] = j; cntv[p] = (float)cv; pr_row[p] = i;
            cell[idx] = p;
        } else cell[idx] = -1;
    } else {
        int idx = (b - NBLK) * 256 + t;
        int i = idx >> 5, d = idx & 31;
        int mode = *modep;
        int xi = x[i]; if (xi < 0) xi = 0; if (xi > 100) xi = 100;
        float s = 0.f;
#pragma unroll
        for (int c = 0; c < 32; c++) s += ldf(emb, xi * 32 + c, mode) * gwf[c * 32 + d];
        bufA[idx] = s;
    }
}

// ---------------- path count wave-per-e1 (b<6144) || agg layer0 (b>=6144) ----------------
__global__ void k_cagg0(const int* __restrict__ row_ptr, const int* __restrict__ col_idx,
                        const int* __restrict__ pr_row, int* __restrict__ pcur,
                        const float* __restrict__ bufA, const float* __restrict__ dinv,
                        const float* __restrict__ gbf, float* __restrict__ bufB) {
    int t = threadIdx.x;
    int b = blockIdx.x;
    if (b < 6144) {
        int wid = b * 4 + (t >> 6);
        int lane = t & 63;
        if (wid >= row_ptr[NN]) return;
        int i = pr_row[wid], k = col_idx[wid];
        int base = i * NN;
        int kb = row_ptr[k], ke = row_ptr[k + 1];
        for (int e = kb + lane; e < ke; e += 64) atomicAdd(&pcur[base + col_idx[e]], 1);
    } else {
        int idx = (b - 6144) * 256 + t;
        int i = idx >> 5, d = idx & 31;
        int base = row_ptr[i], len = row_ptr[i + 1] - base;
        float di = dinv[i];
        float acc = di * bufA[i * 32 + d];
        for (int e = 0; e < len; e++) { int c = col_idx[base + e]; acc += dinv[c] * bufA[c * 32 + d]; }
        bufB[idx] = di * acc + gbf[d];
    }
}

// ---------------- per-chunk scan of pcur (b<2304) || column stats of bufB -> nrm0 (b==2304) ----------------
__global__ void k_s1st0(int* __restrict__ pcur, int* __restrict__ bsum,
                        const float* __restrict__ bufB, float* __restrict__ nrm0) {
    int t = threadIdx.x;
    int b = blockIdx.x;
    if (b < NBLK) {
        __shared__ int s[256];
        int n = b * 256 + t;
        int v = pcur[n];
        s[t] = v;
        __syncthreads();
        for (int off = 1; off < 256; off <<= 1) {
            int tmp = (t >= off) ? s[t - off] : 0;
            __syncthreads();
            s[t] += tmp;
            __syncthreads();
        }
        pcur[n] = s[t] - v;
        if (t == 255) bsum[b] = s[255];
    } else {
        __shared__ float r1[256], r2[256];
        int dd = t & 31, g = t >> 5;
        float s = 0.f, s2 = 0.f;
        for (int r = g; r < NN; r += 8) { float v = bufB[r * 32 + dd]; s += v; s2 += v * v; }
        r1[t] = s; r2[t] = s2;
        __syncthreads();
        if (t < 32) {
            float a = 0.f, b2 = 0.f;
            for (int k = 0; k < 8; k++) { a += r1[k * 32 + t]; b2 += r2[k * 32 + t]; }
            float mean = a / (float)NN;
            float var = b2 / (float)NN - mean * mean;
            nrm0[t] = mean;
            nrm0[32 + t] = rsqrtf(fmaxf(var, 0.f) + 1e-5f);
        }
    }
}

// ---------------- block-sum scan (b==0) || matw1 w/ inline norm0 (b>=1) ----------------
__global__ void k_s2mw1(const int* __restrict__ bsum, int* __restrict__ boff,
                        const float* __restrict__ bufB, const float* __restrict__ nrm0,
                        const float* __restrict__ gwf, float* __restrict__ bufA) {
    int t = threadIdx.x;
    if (blockIdx.x == 0) {
        __shared__ int s[256];
        int b9[9]; int s9 = 0;
#pragma unroll
        for (int q = 0; q < 9; q++) { b9[q] = bsum[t * 9 + q]; s9 += b9[q]; }
        s[t] = s9;
        __syncthreads();
        for (int off = 1; off < 256; off <<= 1) {
            int tmp = (t >= off) ? s[t - off] : 0;
            __syncthreads();
            s[t] += tmp;
            __syncthreads();
        }
        int run = s[t] - s9;
#pragma unroll
        for (int q = 0; q < 9; q++) { boff[t * 9 + q] = run; run += b9[q]; }
    } else {
        int idx = (blockIdx.x - 1) * 256 + t;
        int i = idx >> 5, d = idx & 31;
        const float* W = gwf + 1024;
        float s = 0.f;
#pragma unroll
        for (int c = 0; c < 32; c++) {
            float hv = fmaxf((bufB[i * 32 + c] - nrm0[c]) * nrm0[32 + c], 0.f);
            s += hv * W[c * 32 + d];
        }
        bufA[idx] = s;
    }
}

// ---------------- path join wave-per-e1 (b<6144) || agg layer1 (b>=6144) ----------------
__global__ void k_jagg1(const int* __restrict__ row_ptr, const int* __restrict__ col_idx,
                        const int* __restrict__ pr_row, int* __restrict__ pcur,
                        const int* __restrict__ boff, int2* __restrict__ paths2, int cap,
                        const float* __restrict__ bufA, const float* __restrict__ dinv,
                        const float* __restrict__ gbf, float* __restrict__ bufB) {
    int t = threadIdx.x;
    int b = blockIdx.x;
    if (b < 6144) {
        int wid = b * 4 + (t >> 6);
        int lane = t & 63;
        if (wid >= row_ptr[NN]) return;
        int i = pr_row[wid], k = col_idx[wid];
        int base = i * NN;
        int kb = row_ptr[k], ke = row_ptr[k + 1];
        for (int e = kb + lane; e < ke; e += 64) {
            int celln = base + col_idx[e];
            int slot = boff[celln >> 8] + atomicAdd(&pcur[celln], 1);
            if (slot < cap) paths2[slot] = make_int2(wid, e);
        }
    } else {
        int idx = (b - 6144) * 256 + t;
        int i = idx >> 5, d = idx & 31;
        int base = row_ptr[i], len = row_ptr[i + 1] - base;
        float di = dinv[i];
        float acc = di * bufA[i * 32 + d];
        for (int e = 0; e < len; e++) { int c = col_idx[base + e]; acc += dinv[c] * bufA[c * 32 + d]; }
        bufB[idx] = di * acc + gbf[32 + d];
    }
}

// ---------------- column stats of bufB -> nrm1 ----------------
__global__ void k_st1(const float* __restrict__ bufB, float* __restrict__ nrm1) {
    __shared__ float r1[256], r2[256];
    int t = threadIdx.x;
    int dd = t & 31, g = t >> 5;
    float s = 0.f, s2 = 0.f;
    for (int r = g; r < NN; r += 8) { float v = bufB[r * 32 + dd]; s += v; s2 += v * v; }
    r1[t] = s; r2[t] = s2;
    __syncthreads();
    if (t < 32) {
        float a = 0.f, b2 = 0.f;
        for (int k = 0; k < 8; k++) { a += r1[k * 32 + t]; b2 += r2[k * 32 + t]; }
        float mean = a / (float)NN;
        float var = b2 / (float)NN - mean * mean;
        nrm1[t] = mean;
        nrm1[32 + t] = rsqrtf(fmaxf(var, 0.f) + 1e-5f);
    }
}

// ---------------- edge MLP w/ inline norm1 (b<3072) || h write (b>=3072) ----------------
__global__ void k_emlp(const float* __restrict__ bufB, const float* __restrict__ nrm1,
                       const int* __restrict__ row_ptr, const int* __restrict__ col_idx,
                       const int* __restrict__ pr_row, const float* __restrict__ cntv,
                       const float* __restrict__ w1f, const float* __restrict__ b1f,
                       const float* __restrict__ w2f, const float* __restrict__ b2f,
                       float* __restrict__ xep, float* __restrict__ mulp, float* __restrict__ h) {
    int t = threadIdx.x;
    int b = blockIdx.x;
    if (b < 3072) {
        int d = t & 31;
        int p = b * 8 + (t >> 5);
        if (p >= row_ptr[NN]) {
            if (p < NE) { xep[p * 32 + d] = 0.f; mulp[p * 32 + d] = 0.f; }
            return;
        }
        int i = pr_row[p], j = col_idx[p];
        float a1 = b1f[d], a2 = b2f[d];
#pragma unroll
        for (int c = 0; c < 32; c++) {
            float hv = fmaxf((bufB[i * 32 + c] - nrm1[c]) * nrm1[32 + c], 0.f);
            a1 += hv * w1f[c * 32 + d];
            a2 += hv * w2f[c * 32 + d];
        }
#pragma unroll
        for (int c = 0; c < 32; c++) {
            float hv = fmaxf((bufB[j * 32 + c] - nrm1[c]) * nrm1[32 + c], 0.f);
            a1 += hv * w1f[(32 + c) * 32 + d];
            a2 += hv * w2f[(32 + c) * 32 + d];
        }
        float cv = cntv[p];
        xep[p * 32 + d]  = cv * fmaxf(a1, 0.f);
        mulp[p * 32 + d] = cv * fmaxf(a2, 0.f);
    } else {
        int idx = (b - 3072) * 256 + t;
        int d = idx & 31;
        h[idx] = fmaxf((bufB[idx] - nrm1[d]) * nrm1[32 + d], 0.f);
    }
}

// ---------------- fused: per-cell path gather + z + masked stats (16 replicas) ----------------
__global__ __launch_bounds__(256, 4) void k_big(const int* __restrict__ pcur, const int* __restrict__ boff,
                                                const int2* __restrict__ paths2,
                                                const int* __restrict__ cell,
                                                const float4* __restrict__ xep4, const float4* __restrict__ mulp4,
                                                const float* __restrict__ w3q,
                                                float* __restrict__ stats, int* __restrict__ done,
                                                float* __restrict__ nrm, int cap) {
    __shared__ float sS1[32], sS2[32];
    __shared__ float sCm;
    __shared__ int amlast;
    int t = threadIdx.x, lane = t & 63;
    int b = blockIdx.x;
    int n = b * 256 + t;
    if (t == 0) sCm = 0.f;
    if (t < 32) { sS1[t] = 0.f; sS2[t] = 0.f; }
    __syncthreads();
    int bo = boff[b];
    int p1 = bo + pcur[n];
    int p0 = (t == 0) ? bo : bo + pcur[n - 1];
    if (p0 > cap) p0 = cap; if (p1 > cap) p1 = cap;
    float4 a0 = {0.f,0.f,0.f,0.f}, a1 = a0, a2 = a0, a3 = a0, a4 = a0, a5 = a0, a6 = a0, a7 = a0;
    for (int p = p0; p < p1; p++) {
        int2 rec = paths2[p];
        const float4* xr = xep4 + rec.x * 8;
        const float4* mr = mulp4 + rec.y * 8;
        float4 xv, mv;
        xv = xr[0]; mv = mr[0]; a0.x += xv.x*mv.x; a0.y += xv.y*mv.y; a0.z += xv.z*mv.z; a0.w += xv.w*mv.w;
        xv = xr[1]; mv = mr[1]; a1.x += xv.x*mv.x; a1.y += xv.y*mv.y; a1.z += xv.z*mv.z; a1.w += xv.w*mv.w;
        xv = xr[2]; mv = mr[2]; a2.x += xv.x*mv.x; a2.y += xv.y*mv.y; a2.z += xv.z*mv.z; a2.w += xv.w*mv.w;
        xv = xr[3]; mv = mr[3]; a3.x += xv.x*mv.x; a3.y += xv.y*mv.y; a3.z += xv.z*mv.z; a3.w += xv.w*mv.w;
        xv = xr[4]; mv = mr[4]; a4.x += xv.x*mv.x; a4.y += xv.y*mv.y; a4.z += xv.z*mv.z; a4.w += xv.w*mv.w;
        xv = xr[5]; mv = mr[5]; a5.x += xv.x*mv.x; a5.y += xv.y*mv.y; a5.z += xv.z*mv.z; a5.w += xv.w*mv.w;
        xv = xr[6]; mv = mr[6]; a6.x += xv.x*mv.x; a6.y += xv.y*mv.y; a6.z += xv.z*mv.z; a6.w += xv.w*mv.w;
        xv = xr[7]; mv = mr[7]; a7.x += xv.x*mv.x; a7.y += xv.y*mv.y; a7.z += xv.z*mv.z; a7.w += xv.w*mv.w;
    }
    bool adj = cell[n] >= 0;
    float af = adj ? 1.f : 0.f;
    float msk = (p1 > p0 || adj) ? 1.f : 0.f;
#pragma unroll
    for (int ch = 0; ch < 2; ch++) {
        float v[32];
#pragma unroll
        for (int j = 0; j < 16; j++) {
            int dd = ch * 16 + j;
            const float4* wr = (const float4*)(w3q + dd * 36);   // wave-uniform -> s_load
            float4 wv = wr[8];
            float z = wv.y + af * wv.x;
            wv = wr[0]; DOT4(z, a0, wv);
            wv = wr[1]; DOT4(z, a1, wv);
            wv = wr[2]; DOT4(z, a2, wv);
            wv = wr[3]; DOT4(z, a3, wv);
            wv = wr[4]; DOT4(z, a4, wv);
            wv = wr[5]; DOT4(z, a5, wv);
            wv = wr[6]; DOT4(z, a6, wv);
            wv = wr[7]; DOT4(z, a7, wv);
            v[j] = msk * z;
            v[16 + j] = msk * z * z;
        }
#pragma unroll
        for (int i2 = 0; i2 < 32; i2++) v[i2] += __shfl_xor(v[i2], 32);
        redRound<16, 16>(v, lane);
        redRound<8, 8>(v, lane);
        redRound<4, 4>(v, lane);
        redRound<2, 2>(v, lane);
        redRound<1, 1>(v, lane);
        if (lane < 32) {
            if (lane < 16) atomicAdd(&sS1[ch * 16 + lane], v[0]);
            else           atomicAdd(&sS2[ch * 16 + lane - 16], v[0]);
        }
    }
    {
        float cm2 = msk;
        for (int off = 32; off >= 1; off >>= 1) cm2 += __shfl_xor(cm2, off);
        if (lane == 0) atomicAdd(&sCm, cm2);
    }
    __syncthreads();
    float* srep = stats + (b & (NREP - 1)) * 80;   // replica: own cache lines
    if (t < 32) {
        atomicAdd(&srep[t], sS1[t]);
        atomicAdd(&srep[32 + t], sS2[t]);
    }
    if (t == 32) atomicAdd(&srep[64], sCm);
    __syncthreads();
    if (t == 0) {
        __threadfence();
        amlast = (atomicAdd(done, 1) == NBLK - 1) ? 1 : 0;
    }
    __syncthreads();
    if (amlast && t < 32) {
        float sum1 = 0.f, sum2 = 0.f;
        for (int r = 0; r < NREP; r++) {
            sum1 += aread(&stats[r * 80 + t]);
            sum2 += aread(&stats[r * 80 + 32 + t]);
        }
        float cmv = 0.f;
        for (int r = 0; r < NREP; r++) cmv += aread(&stats[r * 80 + 64]);
        if (cmv < 1.f) cmv = 1.f;
        float mean = sum1 / cmv;
        float var = sum2 / cmv - mean * mean;
        nrm[t] = mean;
        nrm[32 + t] = rsqrtf(fmaxf(var, 0.f) + 1e-5f);
    }
}

// ---------------- output: C at pos pairs via path lists, norm, sym, linear ----------------
__global__ void k_out(const int* __restrict__ pos, const int* __restrict__ pcur,
                      const int* __restrict__ boff, const int2* __restrict__ paths2,
                      const int* __restrict__ cell,
                      const float* __restrict__ xep, const float* __restrict__ mulp,
                      const float* __restrict__ h,
                      const float* __restrict__ w3q,
                      const float* __restrict__ nrm,
                      const float* __restrict__ linf, const float* __restrict__ linb,
                      const int* __restrict__ modep, int cap, void* __restrict__ outp) {
    __shared__ float Cb[4][2][32];
    int t = threadIdx.x;
    int w = t >> 6, lane = t & 63, d = lane & 31, dir = lane >> 5;
    int p = blockIdx.x * 4 + w;
    int a = pos[2 * p], b = pos[2 * p + 1];
    if ((unsigned)a >= (unsigned)NN) a = 0;
    if ((unsigned)b >= (unsigned)NN) b = 0;
    int r = dir ? b : a;
    int cc = dir ? a : b;
    int n = r * NN + cc;
    int nb = n >> 8;
    int p1 = boff[nb] + pcur[n];
    int p0 = ((n & 255) == 0) ? boff[nb] : boff[nb] + pcur[n - 1];
    if (p0 > cap) p0 = cap; if (p1 > cap) p1 = cap;
    float acc = 0.f;
    for (int q = p0; q < p1; q++) {
        int2 rec = paths2[q];
        acc += xep[rec.x * 32 + d] * mulp[rec.y * 32 + d];
    }
    Cb[w][dir][d] = acc;
    bool adj = cell[n] >= 0;
    float msk = (p1 > p0 || adj) ? 1.f : 0.f;
    __syncthreads();
    float z = w3q[d * 36 + 33] + (adj ? 1.f : 0.f) * w3q[d * 36 + 32];
#pragma unroll
    for (int c = 0; c < 32; c++) z += Cb[w][dir][c] * w3q[d * 36 + c];
    float zn = fmaxf((z - nrm[d]) * nrm[32 + d], 0.f);
    float zp = __shfl_xor(zn, 32);
    float symd = msk * zn * zp;
    float xxd = h[a * 32 + d] * h[b * 32 + d];
    float contrib = symd * linf[d] + xxd * linf[32 + d];
    for (int off = 16; off >= 1; off >>= 1) contrib += __shfl_xor(contrib, off);
    if (lane == 0) {
        float v = contrib + linb[0];
        v = fminf(fmaxf(v, -1e4f), 1e4f);
        if (*modep) ((bf16*)outp)[p] = __float2bfloat16(v);
        else        ((float*)outp)[p] = v;
    }
}

extern "C" void kernel_launch(void* const* d_in, const int* in_sizes, int n_in,
                              void* d_out, int out_size, void* d_ws, size_t ws_size,
                              hipStream_t stream) {
    const void* px  = d_in[0];  const void* pei = d_in[1];  const void* ppos = d_in[2];
    const void* pemb = d_in[3]; const void* pgW = d_in[4];  const void* pgB  = d_in[5];
    const void* pm1W = d_in[6]; const void* pm1B = d_in[7]; const void* pm2W = d_in[8];
    const void* pm2B = d_in[9]; const void* pm3W = d_in[10]; const void* pm3B = d_in[11];
    const void* plW = d_in[12]; const void* plB = d_in[13];
    {
        int c2048 = 0, c64 = 0, c32 = 0;
        for (int i = 0; i < n_in; i++) {
            int s = in_sizes[i]; const void* p = d_in[i];
            switch (s) {
                case 768:   px = p; break;
                case 49152: pei = p; break;
                case 8192:  ppos = p; break;
                case 3232:  pemb = p; break;
                case 2048:  if (c2048 == 0) pgW = p; else if (c2048 == 1) pm1W = p; else pm2W = p; c2048++; break;
                case 64:    if (c64 == 0) pgB = p; else plW = p; c64++; break;
                case 32:    if (c32 == 0) pm1B = p; else if (c32 == 1) pm2B = p; else pm3B = p; c32++; break;
                case 1056:  pm3W = p; break;
                case 1:     plB = p; break;
                default: break;
            }
        }
    }

    char* ws = (char*)d_ws;
    size_t off = 0;
    auto alloc = [&](size_t bytes) -> void* {
        void* pp = ws + off;
        off += (bytes + 255) & ~(size_t)255;
        return pp;
    };
    int*   cell    = (int*)alloc(NCELL * 4);
    int*   pcur    = (int*)alloc(NCELL * 4);
    int*   rowlen  = (int*)alloc(NN * 4);
    int*   row_ptr = (int*)alloc((NN + 1) * 4);
    int*   col_idx = (int*)alloc(NE * 4);
    float* cntv    = (float*)alloc(NE * 4);
    int*   pr_row  = (int*)alloc(NE * 4);
    int*   cursor  = (int*)alloc(NN * 4);
    float* dinv    = (float*)alloc(NN * 4);
    float* h       = (float*)alloc(NN * 32 * 4);
    float* bufA    = (float*)alloc(NN * 32 * 4);
    float* bufB    = (float*)alloc(NN * 32 * 4);
    float* xep     = (float*)alloc(NE * 32 * 4);
    float* mulp    = (float*)alloc(NE * 32 * 4);
    float* stats   = (float*)alloc(NREP * 80 * 4);
    float* nrm     = (float*)alloc(64 * 4);
    float* nrm0    = (float*)alloc(64 * 4);
    float* nrm1    = (float*)alloc(64 * 4);
    float* gwf     = (float*)alloc(2048 * 4);
    float* gbf     = (float*)alloc(64 * 4);
    float* w1f     = (float*)alloc(2048 * 4);
    float* b1f     = (float*)alloc(32 * 4);
    float* w2f     = (float*)alloc(2048 * 4);
    float* b2f     = (float*)alloc(32 * 4);
    float* w3q     = (float*)alloc(32 * 36 * 4);
    float* linf    = (float*)alloc(64 * 4);
    float* linb    = (float*)alloc(4);
    int*   modeg   = (int*)alloc(4);
    int*   dcs     = (int*)alloc(8 * 4);
    int*   bsum    = (int*)alloc(NBLK * 4);
    int*   boff    = (int*)alloc(NBLK * 4);
    size_t remain = (ws_size > off) ? (ws_size - off) : 0;
    int cap = (int)(remain / 8);
    if (cap > (1 << 20)) cap = (1 << 20);
    int2*  paths2  = (int2*)alloc((size_t)cap * 8);

    hipMemsetAsync(cell, 0, (size_t)NCELL * 4, stream);
    hipMemsetAsync(pcur, 0, (size_t)NCELL * 4, stream);
    k_conv<<<2, 256, 0, stream>>>(pgW, pgB, pm1W, pm1B, pm2W, pm2B, pm3W, pm3B, plW, plB,
                                  pemb, stats, cursor, rowlen, dcs, modeg,
                                  gwf, gbf, w1f, b1f, w2f, b2f, w3q, linf, linb);
    k_scatter<<<96, 256, 0, stream>>>((const int*)pei, cell, rowlen, row_ptr, dinv, &dcs[0]);
    k_fw0<<<NBLK + 96, 256, 0, stream>>>(cell, row_ptr, cursor, col_idx, cntv, pr_row,
                                         (const int*)px, pemb, modeg, gwf, bufA);
    k_cagg0<<<6144 + 96, 256, 0, stream>>>(row_ptr, col_idx, pr_row, pcur, bufA, dinv, gbf, bufB);
    k_s1st0<<<NBLK + 1, 256, 0, stream>>>(pcur, bsum, bufB, nrm0);
    k_s2mw1<<<1 + 96, 256, 0, stream>>>(bsum, boff, bufB, nrm0, gwf, bufA);
    k_jagg1<<<6144 + 96, 256, 0, stream>>>(row_ptr, col_idx, pr_row, pcur, boff, paths2, cap,
                                           bufA, dinv, gbf, bufB);
    k_st1<<<1, 256, 0, stream>>>(bufB, nrm1);
    k_emlp<<<3072 + 96, 256, 0, stream>>>(bufB, nrm1, row_ptr, col_idx, pr_row, cntv,
                                          w1f, b1f, w2f, b2f, xep, mulp, h);
    k_big<<<NBLK, 256, 0, stream>>>(pcur, boff, paths2, cell, (const float4*)xep, (const float4*)mulp,
                                    w3q, stats, &dcs[1], nrm, cap);
    k_out<<<NPOS / 4, 256, 0, stream>>>((const int*)ppos, pcur, boff, paths2, cell, xep, mulp, h,
                                        w3q, nrm, linf, linb, modeg, cap, d_out);
}